// Round 5
// baseline (163.213 us; speedup 1.0000x reference)
//
#include <hip/hip_runtime.h>
#include <hip/hip_bf16.h>

typedef __attribute__((ext_vector_type(8))) short bf16x8;
typedef __attribute__((ext_vector_type(4))) float f32x4;

#define NPB 16   // 4 waves/block, 4 nodes per wave

__device__ __forceinline__ short f2bf(float f) {
  unsigned u = __float_as_uint(f);
  u += 0x7fffu + ((u >> 16) & 1u);   // RNE to bf16
  return (short)(u >> 16);
}

__device__ __forceinline__ bf16x8 cvt8(float4 A, float4 B) {
  union { bf16x8 v; __hip_bfloat162 h[4]; } u;
  u.h[0] = __float22bfloat162_rn(make_float2(A.x, A.y));
  u.h[1] = __float22bfloat162_rn(make_float2(A.z, A.w));
  u.h[2] = __float22bfloat162_rn(make_float2(B.x, B.y));
  u.h[3] = __float22bfloat162_rn(make_float2(B.z, B.w));
  return u.v;
}

__device__ __forceinline__ bf16x8 ldsfrag(const int* p) {
  union { int4 i; bf16x8 b; } u;
  u.i = *reinterpret_cast<const int4*>(p);
  return u.b;
}

__device__ __forceinline__ float silu(float x) {
  return __fdividef(x, 1.f + __expf(-x));
}

// One wave per node (32 edges = 2 x 16-row tiles), 4 nodes per wave.
// hT = A(W1^T tile) * B(s^T); D leaves each lane holding h of ONE edge ->
// ready A-frag of h under k-permutation pi(c,j) folded into W2 staging.
// Right-branch bias rides in the spare k=20 slot of the padded expansion.
// All per-body loads: wave-uniform SGPR base + fixed per-lane voffset +
// compile-time immediate -> near-zero per-load VALU.
__global__ __launch_bounds__(256) void deepdft_v5(
    const float* __restrict__ S,     // [N,K,1,32]
    const float* __restrict__ V,     // [N,K,3,32]
    const float* __restrict__ EXPN,  // [N,K,20]
    const float* __restrict__ DIR,   // [N,K,3]
    const float* __restrict__ MASK,  // [N,K,1]
    const float* __restrict__ DIST,  // [N,K,1]
    const float* __restrict__ W1,    // [32,32]
    const float* __restrict__ B1,    // [32]
    const float* __restrict__ W2,    // [32,96]
    const float* __restrict__ B2,    // [96]
    const float* __restrict__ WR,    // [20,96]
    const float* __restrict__ BR,    // [96]
    float* __restrict__ OUT,         // [N,1,32] ++ [N,3,32]
    int n_nodes)
{
  __shared__ int wlds[14][256];   // 14 fragment tiles x 64 lanes x 16B

  const int tid = threadIdx.x, wid = tid >> 6, l = tid & 63;
  const int col16 = l & 15, c = l >> 4, kc = c << 3;

  // per-lane element offsets (computed once)
  const int s_off   = col16 * 32 + kc;
  const int e_off   = col16 * 20 + ((c < 2) ? kc : 16);
  const int v_off   = (c << 2) * 96 + col16;   // 384c + col16
  const int dm_off  = c << 2;                  // 4c
  const int dir_off = 12 * c;

  // ---- pipeline registers ----
  float4 sS0, sS1, sE0, sE1;
  float sv[24], sd[4], smk[4], sdir[12];
  float acc[8];

  auto issueS = [&](int ebase) {
    const float* Sb = S + (size_t)ebase * 32;
    sS0 = *reinterpret_cast<const float4*>(Sb + s_off);
    sS1 = *reinterpret_cast<const float4*>(Sb + s_off + 4);
    const float* Eb = EXPN + (size_t)ebase * 20;
    if (c < 2) {
      sE0 = *reinterpret_cast<const float4*>(Eb + e_off);
      sE1 = *reinterpret_cast<const float4*>(Eb + e_off + 4);
    } else if (c == 2) {
      sE0 = *reinterpret_cast<const float4*>(Eb + e_off);
      sE1 = make_float4(1.f, 0.f, 0.f, 0.f);      // k=20 slot = 1 -> +br
    } else {
      sE0 = make_float4(0.f, 0.f, 0.f, 0.f);
      sE1 = make_float4(0.f, 0.f, 0.f, 0.f);
    }
  };

  auto issueV = [&](int ebase) {
    const float* Vb = V + (size_t)ebase * 96;
    const float* Db = DIST + ebase;
    const float* Mb = MASK + ebase;
    const float* Rb = DIR + (size_t)ebase * 3;
    #pragma unroll
    for (int r = 0; r < 4; ++r) {
      sd[r]  = Db[dm_off + r];
      smk[r] = Mb[dm_off + r];
      sdir[3*r+0] = Rb[dir_off + 3*r + 0];
      sdir[3*r+1] = Rb[dir_off + 3*r + 1];
      sdir[3*r+2] = Rb[dir_off + 3*r + 2];
      #pragma unroll
      for (int t = 0; t < 2; ++t)
        #pragma unroll
        for (int ax = 0; ax < 3; ++ax)
          sv[(r*2 + t)*3 + ax] = Vb[v_off + r*96 + ax*32 + t*16];
    }
  };

  const int nbase = blockIdx.x * NPB + (wid << 2);
  int n0 = nbase; if (n0 >= n_nodes) n0 = n_nodes - 1;

  // cold-start loads issued BEFORE weight staging: latency hidden by staging
  issueS(n0 << 5);
  issueV(n0 << 5);

  // ---- stage weight fragments (bf16) into LDS, split across waves ----
  for (int t = wid; t < 14; t += 4) {
    int q[4];
    #pragma unroll
    for (int jj = 0; jj < 4; ++jj) {
      float f0, f1;
      if (t < 2) {                       // W1^T A-frag (== W1 B-frag data)
        int k0 = kc + 2*jj;
        int co = (t << 4) + col16;
        f0 = W1[k0*32 + co]; f1 = W1[(k0+1)*32 + co];
      } else if (t < 8) {                // W2 B-frag, k permuted by pi(c,j)
        int j0 = 2*jj;
        int feat = (j0 < 4) ? (4*c + j0) : (16 + 4*c + (j0 - 4));
        int co = ((t-2) << 4) + col16;
        f0 = W2[feat*96 + co]; f1 = W2[(feat+1)*96 + co];
      } else {                           // WR B-frag, row20 = BR (bias), rest 0
        int k0 = kc + 2*jj;
        int co = ((t-8) << 4) + col16;
        f0 = (k0   < 20) ? WR[k0*96 + co]     : ((k0   == 20) ? BR[co] : 0.f);
        f1 = (k0+1 < 20) ? WR[(k0+1)*96 + co] : ((k0+1 == 20) ? BR[co] : 0.f);
      }
      q[jj] = ((int)(unsigned short)f2bf(f0)) |
              (((int)(unsigned short)f2bf(f1)) << 16);
    }
    *reinterpret_cast<int4*>(&wlds[t][l << 2]) = make_int4(q[0], q[1], q[2], q[3]);
  }

  // b1 per-lane (feature = 16t + 4c + r), b2 per-lane scalars
  f32x4 b1a, b1b;
  {
    float4 t0 = *reinterpret_cast<const float4*>(B1 + 4*c);
    float4 t1 = *reinterpret_cast<const float4*>(B1 + 16 + 4*c);
    b1a[0]=t0.x; b1a[1]=t0.y; b1a[2]=t0.z; b1a[3]=t0.w;
    b1b[0]=t1.x; b1b[1]=t1.y; b1b[2]=t1.z; b1b[3]=t1.w;
  }
  float b2v[6];
  #pragma unroll
  for (int t = 0; t < 6; ++t) b2v[t] = B2[(t << 4) + col16];

  __syncthreads();

  const bf16x8 w1a0 = ldsfrag(&wlds[0][l << 2]);
  const bf16x8 w1a1 = ldsfrag(&wlds[1][l << 2]);

  // computes the currently-staged edge-group; optionally prefetches ebNext
  auto body = [&](int ebNext, bool pf) {
    bf16x8 bs = cvt8(sS0, sS1);
    bf16x8 ae = cvt8(sE0, sE1);
    if (pf) issueS(ebNext);   // S/EXPN consumed -> re-issue immediately

    const f32x4 z = {0.f, 0.f, 0.f, 0.f};
    // right branch (independent of h chain; bias via k=20)
    f32x4 rA0 = __builtin_amdgcn_mfma_f32_16x16x32_bf16(ae, ldsfrag(&wlds[ 8][l<<2]), z, 0,0,0);
    f32x4 rA1 = __builtin_amdgcn_mfma_f32_16x16x32_bf16(ae, ldsfrag(&wlds[ 9][l<<2]), z, 0,0,0);
    f32x4 rB0 = __builtin_amdgcn_mfma_f32_16x16x32_bf16(ae, ldsfrag(&wlds[10][l<<2]), z, 0,0,0);
    f32x4 rB1 = __builtin_amdgcn_mfma_f32_16x16x32_bf16(ae, ldsfrag(&wlds[11][l<<2]), z, 0,0,0);
    f32x4 rC0 = __builtin_amdgcn_mfma_f32_16x16x32_bf16(ae, ldsfrag(&wlds[12][l<<2]), z, 0,0,0);
    f32x4 rC1 = __builtin_amdgcn_mfma_f32_16x16x32_bf16(ae, ldsfrag(&wlds[13][l<<2]), z, 0,0,0);

    // hT: D row = feature, col = edge -> lane-local h row per edge
    f32x4 h0 = __builtin_amdgcn_mfma_f32_16x16x32_bf16(w1a0, bs, b1a, 0,0,0);
    f32x4 h1 = __builtin_amdgcn_mfma_f32_16x16x32_bf16(w1a1, bs, b1b, 0,0,0);

    float wr_[4];
    #pragma unroll
    for (int r = 0; r < 4; ++r) {
      float wv = 0.f;
      if (sd[r] < 5.f)
        wv = smk[r] * 0.5f * (__cosf(0.62831853071795865f * sd[r]) + 1.f);
      wr_[r] = wv;
    }

    bf16x8 ah;   // A-frag of h under pi(c,j)
    {
      union { bf16x8 v; __hip_bfloat162 h[4]; } u;
      u.h[0] = __float22bfloat162_rn(make_float2(silu(h0[0]), silu(h0[1])));
      u.h[1] = __float22bfloat162_rn(make_float2(silu(h0[2]), silu(h0[3])));
      u.h[2] = __float22bfloat162_rn(make_float2(silu(h1[0]), silu(h1[1])));
      u.h[3] = __float22bfloat162_rn(make_float2(silu(h1[2]), silu(h1[3])));
      ah = u.v;
    }

    #pragma unroll
    for (int tt = 0; tt < 2; ++tt) {
      f32x4 lA = __builtin_amdgcn_mfma_f32_16x16x32_bf16(ah, ldsfrag(&wlds[2+tt][l<<2]), z, 0,0,0);
      f32x4 lB = __builtin_amdgcn_mfma_f32_16x16x32_bf16(ah, ldsfrag(&wlds[4+tt][l<<2]), z, 0,0,0);
      f32x4 lC = __builtin_amdgcn_mfma_f32_16x16x32_bf16(ah, ldsfrag(&wlds[6+tt][l<<2]), z, 0,0,0);
      f32x4 rA = tt ? rA1 : rA0;
      f32x4 rB = tt ? rB1 : rB0;
      f32x4 rC = tt ? rC1 : rC0;
      #pragma unroll
      for (int r = 0; r < 4; ++r) {
        float la = lA[r] + b2v[tt];
        float lb = lB[r] + b2v[2+tt];
        float lc = lC[r] + b2v[4+tt];
        float ga = wr_[r] * la * rA[r];
        float gb = wr_[r] * lb * rB[r];
        float gc = wr_[r] * lc * rC[r];
        acc[tt] += gb;
        acc[2+tt] = fmaf(sv[(r*2+tt)*3+0], ga, fmaf(sdir[3*r+0], gc, acc[2+tt]));
        acc[4+tt] = fmaf(sv[(r*2+tt)*3+1], ga, fmaf(sdir[3*r+1], gc, acc[4+tt]));
        acc[6+tt] = fmaf(sv[(r*2+tt)*3+2], ga, fmaf(sdir[3*r+2], gc, acc[6+tt]));
      }
    }
    if (pf) issueV(ebNext);   // V consumed -> re-issue for next group
  };

  #pragma unroll 1
  for (int i = 0; i < 4; ++i) {
    int n = nbase + i; if (n >= n_nodes) n = n_nodes - 1;
    int nn = n + 1; if (i == 3 || nn >= n_nodes) nn = n;

    #pragma unroll
    for (int q = 0; q < 8; ++q) acc[q] = 0.f;

    body((n << 5) + 16, true);    // compute eg0, prefetch eg1
    body(nn << 5, i < 3);         // compute eg1, prefetch next node (not on last)

    #pragma unroll
    for (int q = 0; q < 8; ++q) {
      acc[q] += __shfl_xor(acc[q], 16);
      acc[q] += __shfl_xor(acc[q], 32);
    }
    if (l < 16) {
      float* os = OUT + (size_t)n * 32;
      os[col16]      = acc[0];
      os[16 + col16] = acc[1];
      float* ov = OUT + (size_t)n_nodes * 32 + (size_t)n * 96;
      ov[     col16] = acc[2]; ov[16 + col16] = acc[3];
      ov[32 + col16] = acc[4]; ov[48 + col16] = acc[5];
      ov[64 + col16] = acc[6]; ov[80 + col16] = acc[7];
    }
  }
}

extern "C" void kernel_launch(void* const* d_in, const int* in_sizes, int n_in,
                              void* d_out, int out_size, void* d_ws, size_t ws_size,
                              hipStream_t stream) {
  const float* S    = (const float*)d_in[0];
  const float* V    = (const float*)d_in[1];
  const float* EXPN = (const float*)d_in[2];
  const float* DIR  = (const float*)d_in[3];
  const float* MASK = (const float*)d_in[4];
  const float* DIST = (const float*)d_in[5];
  const float* W1   = (const float*)d_in[6];
  const float* B1   = (const float*)d_in[7];
  const float* W2   = (const float*)d_in[8];
  const float* B2   = (const float*)d_in[9];
  const float* WR   = (const float*)d_in[10];
  const float* BR   = (const float*)d_in[11];
  float* OUT = (float*)d_out;

  const int n_nodes = in_sizes[0] / 1024;            // 30000
  const int grid = (n_nodes + NPB - 1) / NPB;        // 1875

  hipLaunchKernelGGL(deepdft_v5, dim3(grid), dim3(256), 0, stream,
                     S, V, EXPN, DIR, MASK, DIST, W1, B1, W2, B2, WR, BR,
                     OUT, n_nodes);
}

// Round 6
// 144.478 us; speedup vs baseline: 1.1297x; 1.1297x over previous
//
#include <hip/hip_runtime.h>
#include <hip/hip_bf16.h>

typedef __attribute__((ext_vector_type(8))) short bf16x8;
typedef __attribute__((ext_vector_type(4))) float f32x4;

__device__ __forceinline__ short f2bf(float f) {
  unsigned u = __float_as_uint(f);
  u += 0x7fffu + ((u >> 16) & 1u);   // RNE to bf16
  return (short)(u >> 16);
}

__device__ __forceinline__ bf16x8 cvt8(float4 A, float4 B) {
  union { bf16x8 v; __hip_bfloat162 h[4]; } u;
  u.h[0] = __float22bfloat162_rn(make_float2(A.x, A.y));
  u.h[1] = __float22bfloat162_rn(make_float2(A.z, A.w));
  u.h[2] = __float22bfloat162_rn(make_float2(B.x, B.y));
  u.h[3] = __float22bfloat162_rn(make_float2(B.z, B.w));
  return u.v;
}

__device__ __forceinline__ bf16x8 ldsfrag(const int4* p) {
  union { int4 i; bf16x8 b; } u;
  u.i = *p;
  return u.b;
}

__device__ __forceinline__ float silu_(float x) {
  return __fdividef(x, 1.f + __expf(-x));
}

// ---- setup: pack the 14 MFMA weight-fragment tiles into d_ws (14 KB) ----
// tile 0..1 : W1^T A-frags;  2..7 : W2 B-frags (k permuted by pi(c,j));
// 8..13 : WR B-frags with row20 = BR (bias rides the spare k slot).
__global__ void pack_weights_kernel(
    const float* __restrict__ W1, const float* __restrict__ W2,
    const float* __restrict__ WR, const float* __restrict__ BR,
    int4* __restrict__ wsf)
{
  const int tid = threadIdx.x, wid = tid >> 6, l = tid & 63;
  const int col16 = l & 15, c = l >> 4, kc = c << 3;
  for (int t = wid; t < 14; t += 4) {
    int q[4];
    #pragma unroll
    for (int jj = 0; jj < 4; ++jj) {
      float f0, f1;
      if (t < 2) {
        int k0 = kc + 2*jj;
        int co = (t << 4) + col16;
        f0 = W1[k0*32 + co]; f1 = W1[(k0+1)*32 + co];
      } else if (t < 8) {
        int j0 = 2*jj;
        int feat = (j0 < 4) ? (4*c + j0) : (16 + 4*c + (j0 - 4));
        int co = ((t-2) << 4) + col16;
        f0 = W2[feat*96 + co]; f1 = W2[(feat+1)*96 + co];
      } else {
        int k0 = kc + 2*jj;
        int co = ((t-8) << 4) + col16;
        f0 = (k0   < 20) ? WR[k0*96 + co]     : ((k0   == 20) ? BR[co] : 0.f);
        f1 = (k0+1 < 20) ? WR[(k0+1)*96 + co] : ((k0+1 == 20) ? BR[co] : 0.f);
      }
      q[jj] = ((int)(unsigned short)f2bf(f0)) |
              (((int)(unsigned short)f2bf(f1)) << 16);
    }
    wsf[t*64 + l] = make_int4(q[0], q[1], q[2], q[3]);
  }
}

// ---- main: one wave per (node, 16-edge half); 4 waves/block = 2 nodes ----
// All loads issued up-front; weights staged from pre-packed d_ws with
// 4 coalesced int4 loads per wave; node halves combined in-block via LDS.
__global__ __launch_bounds__(256) void deepdft_v6(
    const float* __restrict__ S, const float* __restrict__ V,
    const float* __restrict__ EXPN, const float* __restrict__ DIR,
    const float* __restrict__ MASK, const float* __restrict__ DIST,
    const float* __restrict__ B1, const float* __restrict__ B2,
    const int4* __restrict__ wsf,
    float* __restrict__ OUT, int n_nodes)
{
  __shared__ int4  wlds[14][64];
  __shared__ float pbuf[4][128];

  const int tid = threadIdx.x, wid = tid >> 6, l = tid & 63;
  const int col16 = l & 15, c = l >> 4, kc = c << 3;

  const int nd = blockIdx.x * 2 + (wid >> 1);
  const int ncl = (nd < n_nodes) ? nd : (n_nodes - 1);
  const int ebase = (ncl << 5) + ((wid & 1) << 4);

  // ---- stage weights first (so their vmcnt wait doesn't drain node loads) ----
  #pragma unroll
  for (int t = wid; t < 14; t += 4) wlds[t][l] = wsf[t*64 + l];

  // ---- issue ALL per-edge loads up-front (~11.5 KB in flight per wave) ----
  const float* Sb = S + (size_t)ebase * 32;
  float4 sS0 = *reinterpret_cast<const float4*>(Sb + col16*32 + kc);
  float4 sS1 = *reinterpret_cast<const float4*>(Sb + col16*32 + kc + 4);

  const float* Eb = EXPN + (size_t)ebase * 20;
  float4 sE0, sE1;
  if (c < 2) {
    sE0 = *reinterpret_cast<const float4*>(Eb + col16*20 + kc);
    sE1 = *reinterpret_cast<const float4*>(Eb + col16*20 + kc + 4);
  } else if (c == 2) {
    sE0 = *reinterpret_cast<const float4*>(Eb + col16*20 + 16);
    sE1 = make_float4(1.f, 0.f, 0.f, 0.f);      // k=20 slot = 1 -> +br
  } else {
    sE0 = make_float4(0.f, 0.f, 0.f, 0.f);
    sE1 = make_float4(0.f, 0.f, 0.f, 0.f);
  }

  float sv[24], sd[4], smk[4], sdir[12];
  {
    const float* Vb = V + (size_t)ebase * 96;
    const float* Db = DIST + ebase;
    const float* Mb = MASK + ebase;
    const float* Rb = DIR + (size_t)ebase * 3;
    #pragma unroll
    for (int r = 0; r < 4; ++r) {
      const int er = (c << 2) + r;
      sd[r]  = Db[er];
      smk[r] = Mb[er];
      sdir[3*r+0] = Rb[3*er+0];
      sdir[3*r+1] = Rb[3*er+1];
      sdir[3*r+2] = Rb[3*er+2];
      #pragma unroll
      for (int t = 0; t < 2; ++t)
        #pragma unroll
        for (int ax = 0; ax < 3; ++ax)
          sv[(r*2 + t)*3 + ax] = Vb[(size_t)er*96 + ax*32 + t*16 + col16];
    }
  }

  // biases (tiny, L3-hot)
  f32x4 b1a, b1b;
  {
    float4 t0 = *reinterpret_cast<const float4*>(B1 + 4*c);
    float4 t1 = *reinterpret_cast<const float4*>(B1 + 16 + 4*c);
    b1a[0]=t0.x; b1a[1]=t0.y; b1a[2]=t0.z; b1a[3]=t0.w;
    b1b[0]=t1.x; b1b[1]=t1.y; b1b[2]=t1.z; b1b[3]=t1.w;
  }
  float b2v[6];
  #pragma unroll
  for (int t = 0; t < 6; ++t) b2v[t] = B2[(t << 4) + col16];

  __syncthreads();

  // ---- compute one 16-edge body ----
  bf16x8 bs = cvt8(sS0, sS1);
  bf16x8 ae = cvt8(sE0, sE1);
  const f32x4 z = {0.f, 0.f, 0.f, 0.f};

  f32x4 rA0 = __builtin_amdgcn_mfma_f32_16x16x32_bf16(ae, ldsfrag(&wlds[ 8][l]), z, 0,0,0);
  f32x4 rA1 = __builtin_amdgcn_mfma_f32_16x16x32_bf16(ae, ldsfrag(&wlds[ 9][l]), z, 0,0,0);
  f32x4 rB0 = __builtin_amdgcn_mfma_f32_16x16x32_bf16(ae, ldsfrag(&wlds[10][l]), z, 0,0,0);
  f32x4 rB1 = __builtin_amdgcn_mfma_f32_16x16x32_bf16(ae, ldsfrag(&wlds[11][l]), z, 0,0,0);
  f32x4 rC0 = __builtin_amdgcn_mfma_f32_16x16x32_bf16(ae, ldsfrag(&wlds[12][l]), z, 0,0,0);
  f32x4 rC1 = __builtin_amdgcn_mfma_f32_16x16x32_bf16(ae, ldsfrag(&wlds[13][l]), z, 0,0,0);

  // hT: D row = feature, col = edge -> lane-local h row per edge
  f32x4 h0 = __builtin_amdgcn_mfma_f32_16x16x32_bf16(ldsfrag(&wlds[0][l]), bs, b1a, 0,0,0);
  f32x4 h1 = __builtin_amdgcn_mfma_f32_16x16x32_bf16(ldsfrag(&wlds[1][l]), bs, b1b, 0,0,0);

  float wr_[4];
  #pragma unroll
  for (int r = 0; r < 4; ++r) {
    float wv = 0.f;
    if (sd[r] < 5.f)
      wv = smk[r] * 0.5f * (__cosf(0.62831853071795865f * sd[r]) + 1.f);
    wr_[r] = wv;
  }

  bf16x8 ah;   // A-frag of h under pi(c,j)
  {
    union { bf16x8 v; __hip_bfloat162 h[4]; } u;
    u.h[0] = __float22bfloat162_rn(make_float2(silu_(h0[0]), silu_(h0[1])));
    u.h[1] = __float22bfloat162_rn(make_float2(silu_(h0[2]), silu_(h0[3])));
    u.h[2] = __float22bfloat162_rn(make_float2(silu_(h1[0]), silu_(h1[1])));
    u.h[3] = __float22bfloat162_rn(make_float2(silu_(h1[2]), silu_(h1[3])));
    ah = u.v;
  }

  float acc[8] = {0.f,0.f,0.f,0.f,0.f,0.f,0.f,0.f};
  #pragma unroll
  for (int tt = 0; tt < 2; ++tt) {
    f32x4 lA = __builtin_amdgcn_mfma_f32_16x16x32_bf16(ah, ldsfrag(&wlds[2+tt][l]), z, 0,0,0);
    f32x4 lB = __builtin_amdgcn_mfma_f32_16x16x32_bf16(ah, ldsfrag(&wlds[4+tt][l]), z, 0,0,0);
    f32x4 lC = __builtin_amdgcn_mfma_f32_16x16x32_bf16(ah, ldsfrag(&wlds[6+tt][l]), z, 0,0,0);
    f32x4 rA = tt ? rA1 : rA0;
    f32x4 rB = tt ? rB1 : rB0;
    f32x4 rC = tt ? rC1 : rC0;
    #pragma unroll
    for (int r = 0; r < 4; ++r) {
      float la = lA[r] + b2v[tt];
      float lb = lB[r] + b2v[2+tt];
      float lc = lC[r] + b2v[4+tt];
      float ga = wr_[r] * la * rA[r];
      float gb = wr_[r] * lb * rB[r];
      float gc = wr_[r] * lc * rC[r];
      acc[tt] += gb;
      acc[2+tt] = fmaf(sv[(r*2+tt)*3+0], ga, fmaf(sdir[3*r+0], gc, acc[2+tt]));
      acc[4+tt] = fmaf(sv[(r*2+tt)*3+1], ga, fmaf(sdir[3*r+1], gc, acc[4+tt]));
      acc[6+tt] = fmaf(sv[(r*2+tt)*3+2], ga, fmaf(sdir[3*r+2], gc, acc[6+tt]));
    }
  }

  // ---- in-wave reduce over the 16 edges (lane bits 4,5 = c) ----
  #pragma unroll
  for (int q = 0; q < 8; ++q) {
    acc[q] += __shfl_xor(acc[q], 16);
    acc[q] += __shfl_xor(acc[q], 32);
  }
  if (l < 16) {
    #pragma unroll
    for (int q = 0; q < 8; ++q) pbuf[wid][q*16 + col16] = acc[q];
  }
  __syncthreads();

  // ---- combine the two halves of each node and store ----
  const int f = tid & 127, d = tid >> 7;
  const int node = blockIdx.x * 2 + d;
  if (node < n_nodes) {
    float val = pbuf[2*d][f] + pbuf[2*d + 1][f];
    if (f < 32) OUT[(size_t)node * 32 + f] = val;
    else        OUT[(size_t)n_nodes * 32 + (size_t)node * 96 + (f - 32)] = val;
  }
}

extern "C" void kernel_launch(void* const* d_in, const int* in_sizes, int n_in,
                              void* d_out, int out_size, void* d_ws, size_t ws_size,
                              hipStream_t stream) {
  const float* S    = (const float*)d_in[0];
  const float* V    = (const float*)d_in[1];
  const float* EXPN = (const float*)d_in[2];
  const float* DIR  = (const float*)d_in[3];
  const float* MASK = (const float*)d_in[4];
  const float* DIST = (const float*)d_in[5];
  const float* W1   = (const float*)d_in[6];
  const float* B1   = (const float*)d_in[7];
  const float* W2   = (const float*)d_in[8];
  const float* B2   = (const float*)d_in[9];
  const float* WR   = (const float*)d_in[10];
  const float* BR   = (const float*)d_in[11];
  float* OUT = (float*)d_out;
  int4* wsf = (int4*)d_ws;   // 14 KB of packed weight fragments

  const int n_nodes = in_sizes[0] / 1024;            // 30000
  const int grid = (n_nodes + 1) / 2;                // 15000

  hipLaunchKernelGGL(pack_weights_kernel, dim3(1), dim3(256), 0, stream,
                     W1, W2, WR, BR, wsf);
  hipLaunchKernelGGL(deepdft_v6, dim3(grid), dim3(256), 0, stream,
                     S, V, EXPN, DIR, MASK, DIST, B1, B2, wsf, OUT, n_nodes);
}

// Round 7
// 137.039 us; speedup vs baseline: 1.1910x; 1.0543x over previous
//
#include <hip/hip_runtime.h>
#include <hip/hip_bf16.h>

typedef __attribute__((ext_vector_type(8))) short bf16x8;
typedef __attribute__((ext_vector_type(4))) float f32x4;

#define GSTR 68   // floats per er-row of gate buffer (32 f x 2 + 4 pad)

__device__ __forceinline__ short f2bf(float f) {
  unsigned u = __float_as_uint(f);
  u += 0x7fffu + ((u >> 16) & 1u);   // RNE to bf16
  return (short)(u >> 16);
}

__device__ __forceinline__ bf16x8 cvt8(float4 A, float4 B) {
  union { bf16x8 v; __hip_bfloat162 h[4]; } u;
  u.h[0] = __float22bfloat162_rn(make_float2(A.x, A.y));
  u.h[1] = __float22bfloat162_rn(make_float2(A.z, A.w));
  u.h[2] = __float22bfloat162_rn(make_float2(B.x, B.y));
  u.h[3] = __float22bfloat162_rn(make_float2(B.z, B.w));
  return u.v;
}

__device__ __forceinline__ bf16x8 ldsfrag(const int4* p) {
  union { int4 i; bf16x8 b; } u;
  u.i = *p;
  return u.b;
}

__device__ __forceinline__ float silu_(float x) {
  return __fdividef(x, 1.f + __expf(-x));
}

// ---- setup: pack the 14 MFMA weight-fragment tiles into d_ws (14 KB) ----
__global__ void pack_weights_kernel(
    const float* __restrict__ W1, const float* __restrict__ W2,
    const float* __restrict__ WR, const float* __restrict__ BR,
    int4* __restrict__ wsf)
{
  const int tid = threadIdx.x, wid = tid >> 6, l = tid & 63;
  const int col16 = l & 15, c = l >> 4, kc = c << 3;
  for (int t = wid; t < 14; t += 4) {
    int q[4];
    #pragma unroll
    for (int jj = 0; jj < 4; ++jj) {
      float f0, f1;
      if (t < 2) {                       // W1^T A-frags
        int k0 = kc + 2*jj;
        int co = (t << 4) + col16;
        f0 = W1[k0*32 + co]; f1 = W1[(k0+1)*32 + co];
      } else if (t < 8) {                // W2 B-frags, k permuted by pi(c,j)
        int j0 = 2*jj;
        int feat = (j0 < 4) ? (4*c + j0) : (16 + 4*c + (j0 - 4));
        int co = ((t-2) << 4) + col16;
        f0 = W2[feat*96 + co]; f1 = W2[(feat+1)*96 + co];
      } else {                           // WR B-frags, row20 = BR
        int k0 = kc + 2*jj;
        int co = ((t-8) << 4) + col16;
        f0 = (k0   < 20) ? WR[k0*96 + co]     : ((k0   == 20) ? BR[co] : 0.f);
        f1 = (k0+1 < 20) ? WR[(k0+1)*96 + co] : ((k0+1 == 20) ? BR[co] : 0.f);
      }
      q[jj] = ((int)(unsigned short)f2bf(f0)) |
              (((int)(unsigned short)f2bf(f1)) << 16);
    }
    wsf[t*64 + l] = make_int4(q[0], q[1], q[2], q[3]);
  }
}

// ---- main: one wave per node; gates redistributed via LDS so V is read
// as 6 x dwordx4 per lane (1 KB payload/instr) instead of 24 scalars. ----
__global__ __launch_bounds__(256, 4) void deepdft_v7(
    const float* __restrict__ S, const float* __restrict__ V,
    const float* __restrict__ EXPN, const float* __restrict__ DIR,
    const float* __restrict__ MASK, const float* __restrict__ DIST,
    const float* __restrict__ B1, const float* __restrict__ B2,
    const int4* __restrict__ wsf,
    float* __restrict__ OUT, int n_nodes)
{
  __shared__ int4  wlds[14][64];
  __shared__ float glds[4][16 * GSTR];   // per-wave gate buffer (ga,gc pairs)

  const int tid = threadIdx.x, wid = tid >> 6, l = tid & 63;
  const int col16 = l & 15, c = l >> 4, kc = c << 3;
  const int er8 = l >> 2, fo = l & 3;    // V-phase lane mapping

  int n = blockIdx.x * 4 + wid;
  if (n >= n_nodes) n = n_nodes - 1;
  const int eb0 = n << 5, eb1 = eb0 + 16;

  // ---- pipeline registers ----
  float4 sS0, sS1, sE0, sE1;
  float4 vva[6];
  float dv, mv, drv;

  auto issueS = [&](int eb) {
    const float* sp = S + (size_t)(eb + col16) * 32 + kc;
    sS0 = *reinterpret_cast<const float4*>(sp);
    sS1 = *reinterpret_cast<const float4*>(sp + 4);
    const float* ep = EXPN + (size_t)(eb + col16) * 20;
    if (c < 2) {
      sE0 = *reinterpret_cast<const float4*>(ep + kc);
      sE1 = *reinterpret_cast<const float4*>(ep + kc + 4);
    } else if (c == 2) {
      sE0 = *reinterpret_cast<const float4*>(ep + 16);
      sE1 = make_float4(1.f, 0.f, 0.f, 0.f);   // k=20 slot = 1 -> +br
    } else {
      sE0 = make_float4(0.f, 0.f, 0.f, 0.f);
      sE1 = make_float4(0.f, 0.f, 0.f, 0.f);
    }
  };
  auto issueV = [&](int eb) {
    const float* vb = V + (size_t)(eb + er8) * 96 + fo * 8;
    vva[0] = *reinterpret_cast<const float4*>(vb);
    vva[1] = *reinterpret_cast<const float4*>(vb + 4);
    vva[2] = *reinterpret_cast<const float4*>(vb + 32);
    vva[3] = *reinterpret_cast<const float4*>(vb + 36);
    vva[4] = *reinterpret_cast<const float4*>(vb + 64);
    vva[5] = *reinterpret_cast<const float4*>(vb + 68);
  };
  auto issueDMR = [&](int eb) {
    dv  = DIST[eb + col16];                       // wv for er = col16
    mv  = MASK[eb + col16];
    drv = DIR[(size_t)eb * 3 + (l < 48 ? l : 47)];
  };

  // cold-start loads before staging: latency hidden by staging work
  issueS(eb0); issueDMR(eb0); issueV(eb0);

  // ---- stage weights (4 int4 loads/wave from pre-packed d_ws) ----
  #pragma unroll
  for (int t = wid; t < 14; t += 4) wlds[t][l] = wsf[t*64 + l];

  f32x4 b1a, b1b;
  {
    float4 t0 = *reinterpret_cast<const float4*>(B1 + 4*c);
    float4 t1 = *reinterpret_cast<const float4*>(B1 + 16 + 4*c);
    b1a[0]=t0.x; b1a[1]=t0.y; b1a[2]=t0.z; b1a[3]=t0.w;
    b1b[0]=t1.x; b1b[1]=t1.y; b1b[2]=t1.z; b1b[3]=t1.w;
  }
  float b2v[6];
  #pragma unroll
  for (int t = 0; t < 6; ++t) b2v[t] = B2[(t << 4) + col16];

  __syncthreads();

  float part[24];
  #pragma unroll
  for (int q = 0; q < 24; ++q) part[q] = 0.f;
  float accs0 = 0.f, accs1 = 0.f;
  float* gw = &glds[wid][0];
  const f32x4 z = {0.f, 0.f, 0.f, 0.f};

  #pragma unroll
  for (int it = 0; it < 2; ++it) {
    // ================= gate phase (D-layout lanes) =================
    bf16x8 bs = cvt8(sS0, sS1);
    bf16x8 ae = cvt8(sE0, sE1);
    if (it == 0) issueS(eb1);

    // hT: lane-local h row per edge
    f32x4 h0 = __builtin_amdgcn_mfma_f32_16x16x32_bf16(ldsfrag(&wlds[0][l]), bs, b1a, 0,0,0);
    f32x4 h1 = __builtin_amdgcn_mfma_f32_16x16x32_bf16(ldsfrag(&wlds[1][l]), bs, b1b, 0,0,0);
    bf16x8 ah;
    {
      union { bf16x8 v; __hip_bfloat162 h[4]; } u;
      u.h[0] = __float22bfloat162_rn(make_float2(silu_(h0[0]), silu_(h0[1])));
      u.h[1] = __float22bfloat162_rn(make_float2(silu_(h0[2]), silu_(h0[3])));
      u.h[2] = __float22bfloat162_rn(make_float2(silu_(h1[0]), silu_(h1[1])));
      u.h[3] = __float22bfloat162_rn(make_float2(silu_(h1[2]), silu_(h1[3])));
      ah = u.v;
    }

    // wv for this lane's er' = col16, then gather for er = 4c+r
    float wvl = 0.f;
    if (dv < 5.f) wvl = mv * 0.5f * (__cosf(0.62831853071795865f * dv) + 1.f);
    float wv0 = __shfl(wvl, 4*c + 0);
    float wv1 = __shfl(wvl, 4*c + 1);
    float wv2 = __shfl(wvl, 4*c + 2);
    float wv3 = __shfl(wvl, 4*c + 3);

    #pragma unroll
    for (int tt = 0; tt < 2; ++tt) {
      f32x4 rA = __builtin_amdgcn_mfma_f32_16x16x32_bf16(ae, ldsfrag(&wlds[ 8+tt][l]), z, 0,0,0);
      f32x4 rB = __builtin_amdgcn_mfma_f32_16x16x32_bf16(ae, ldsfrag(&wlds[10+tt][l]), z, 0,0,0);
      f32x4 rC = __builtin_amdgcn_mfma_f32_16x16x32_bf16(ae, ldsfrag(&wlds[12+tt][l]), z, 0,0,0);
      f32x4 lA = __builtin_amdgcn_mfma_f32_16x16x32_bf16(ah, ldsfrag(&wlds[ 2+tt][l]), z, 0,0,0);
      f32x4 lB = __builtin_amdgcn_mfma_f32_16x16x32_bf16(ah, ldsfrag(&wlds[ 4+tt][l]), z, 0,0,0);
      f32x4 lC = __builtin_amdgcn_mfma_f32_16x16x32_bf16(ah, ldsfrag(&wlds[ 6+tt][l]), z, 0,0,0);
      #pragma unroll
      for (int r = 0; r < 4; ++r) {
        const float wv = (r==0) ? wv0 : (r==1) ? wv1 : (r==2) ? wv2 : wv3;
        const float ga = wv * (lA[r] + b2v[tt])   * rA[r];
        const float gb = wv * (lB[r] + b2v[2+tt]) * rB[r];
        const float gc = wv * (lC[r] + b2v[4+tt]) * rC[r];
        if (tt == 0) accs0 += gb; else accs1 += gb;
        *reinterpret_cast<float2*>(
            &gw[(4*c + r) * GSTR + 2*(col16 + 16*tt)]) = make_float2(ga, gc);
      }
    }
    __builtin_amdgcn_wave_barrier();

    // ================= V phase (er8/fo lanes) =================
    float d0 = __shfl(drv, 3*er8 + 0);
    float d1 = __shfl(drv, 3*er8 + 1);
    float d2 = __shfl(drv, 3*er8 + 2);
    if (it == 0) issueDMR(eb1);

    float4 gp[4];
    #pragma unroll
    for (int k = 0; k < 4; ++k)
      gp[k] = *reinterpret_cast<const float4*>(&gw[er8 * GSTR + 16*fo + 4*k]);

    #pragma unroll
    for (int ax = 0; ax < 3; ++ax) {
      const float dax = (ax==0) ? d0 : (ax==1) ? d1 : d2;
      #pragma unroll
      for (int j = 0; j < 8; ++j) {
        const float vj  = vva[2*ax + (j>>2)][j&3];
        const float gaj = gp[j>>1][(j&1)*2];
        const float gcj = gp[j>>1][(j&1)*2 + 1];
        part[ax*8+j] = fmaf(vj, gaj, fmaf(dax, gcj, part[ax*8+j]));
      }
    }
    if (it == 0) issueV(eb1);
    __builtin_amdgcn_wave_barrier();   // next item's gate writes stay below
  }

  // ---- reduce over er (lanes stride 4) and store ----
  #pragma unroll
  for (int q = 0; q < 24; ++q) {
    part[q] += __shfl_xor(part[q], 4);
    part[q] += __shfl_xor(part[q], 8);
    part[q] += __shfl_xor(part[q], 16);
    part[q] += __shfl_xor(part[q], 32);
  }
  accs0 += __shfl_xor(accs0, 16); accs0 += __shfl_xor(accs0, 32);
  accs1 += __shfl_xor(accs1, 16); accs1 += __shfl_xor(accs1, 32);

  if (l < 16) {
    OUT[(size_t)n * 32 + col16]      = accs0;
    OUT[(size_t)n * 32 + 16 + col16] = accs1;
  }
  if (l < 4) {
    float* ov = OUT + (size_t)n_nodes * 32 + (size_t)n * 96 + 8*fo;
    #pragma unroll
    for (int ax = 0; ax < 3; ++ax) {
      *reinterpret_cast<float4*>(ov + ax*32) =
          make_float4(part[ax*8+0], part[ax*8+1], part[ax*8+2], part[ax*8+3]);
      *reinterpret_cast<float4*>(ov + ax*32 + 4) =
          make_float4(part[ax*8+4], part[ax*8+5], part[ax*8+6], part[ax*8+7]);
    }
  }
}

extern "C" void kernel_launch(void* const* d_in, const int* in_sizes, int n_in,
                              void* d_out, int out_size, void* d_ws, size_t ws_size,
                              hipStream_t stream) {
  const float* S    = (const float*)d_in[0];
  const float* V    = (const float*)d_in[1];
  const float* EXPN = (const float*)d_in[2];
  const float* DIR  = (const float*)d_in[3];
  const float* MASK = (const float*)d_in[4];
  const float* DIST = (const float*)d_in[5];
  const float* W1   = (const float*)d_in[6];
  const float* B1   = (const float*)d_in[7];
  const float* W2   = (const float*)d_in[8];
  const float* B2   = (const float*)d_in[9];
  const float* WR   = (const float*)d_in[10];
  const float* BR   = (const float*)d_in[11];
  float* OUT = (float*)d_out;
  int4* wsf = (int4*)d_ws;   // 14 KB packed weight fragments

  const int n_nodes = in_sizes[0] / 1024;            // 30000
  const int grid = (n_nodes + 3) / 4;                // 7500

  hipLaunchKernelGGL(pack_weights_kernel, dim3(1), dim3(256), 0, stream,
                     W1, W2, WR, BR, wsf);
  hipLaunchKernelGGL(deepdft_v7, dim3(grid), dim3(256), 0, stream,
                     S, V, EXPN, DIR, MASK, DIST, B1, B2, wsf, OUT, n_nodes);
}

// Round 8
// 133.319 us; speedup vs baseline: 1.2242x; 1.0279x over previous
//
#include <hip/hip_runtime.h>
#include <hip/hip_bf16.h>

typedef __attribute__((ext_vector_type(8))) short bf16x8;
typedef __attribute__((ext_vector_type(4))) float f32x4;

#define GSTR 68   // floats per er-row of gate buffer (32 f x 2 + 4 pad)

__device__ __forceinline__ short f2bf(float f) {
  unsigned u = __float_as_uint(f);
  u += 0x7fffu + ((u >> 16) & 1u);   // RNE to bf16
  return (short)(u >> 16);
}

__device__ __forceinline__ bf16x8 cvt8(float4 A, float4 B) {
  union { bf16x8 v; __hip_bfloat162 h[4]; } u;
  u.h[0] = __float22bfloat162_rn(make_float2(A.x, A.y));
  u.h[1] = __float22bfloat162_rn(make_float2(A.z, A.w));
  u.h[2] = __float22bfloat162_rn(make_float2(B.x, B.y));
  u.h[3] = __float22bfloat162_rn(make_float2(B.z, B.w));
  return u.v;
}

__device__ __forceinline__ bf16x8 ldsfrag(const int4* p) {
  union { int4 i; bf16x8 b; } u;
  u.i = *p;
  return u.b;
}

__device__ __forceinline__ float silu_(float x) {
  return __fdividef(x, 1.f + __expf(-x));
}

// ---- setup: pack the 14 MFMA weight-fragment tiles into d_ws (14 KB) ----
__global__ void pack_weights_kernel(
    const float* __restrict__ W1, const float* __restrict__ W2,
    const float* __restrict__ WR, const float* __restrict__ BR,
    int4* __restrict__ wsf)
{
  const int tid = threadIdx.x, wid = tid >> 6, l = tid & 63;
  const int col16 = l & 15, c = l >> 4, kc = c << 3;
  for (int t = wid; t < 14; t += 4) {
    int q[4];
    #pragma unroll
    for (int jj = 0; jj < 4; ++jj) {
      float f0, f1;
      if (t < 2) {                       // W1^T A-frags
        int k0 = kc + 2*jj;
        int co = (t << 4) + col16;
        f0 = W1[k0*32 + co]; f1 = W1[(k0+1)*32 + co];
      } else if (t < 8) {                // W2 B-frags, k permuted by pi(c,j)
        int j0 = 2*jj;
        int feat = (j0 < 4) ? (4*c + j0) : (16 + 4*c + (j0 - 4));
        int co = ((t-2) << 4) + col16;
        f0 = W2[feat*96 + co]; f1 = W2[(feat+1)*96 + co];
      } else {                           // WR B-frags, row20 = BR
        int k0 = kc + 2*jj;
        int co = ((t-8) << 4) + col16;
        f0 = (k0   < 20) ? WR[k0*96 + co]     : ((k0   == 20) ? BR[co] : 0.f);
        f1 = (k0+1 < 20) ? WR[(k0+1)*96 + co] : ((k0+1 == 20) ? BR[co] : 0.f);
      }
      q[jj] = ((int)(unsigned short)f2bf(f0)) |
              (((int)(unsigned short)f2bf(f1)) << 16);
    }
    wsf[t*64 + l] = make_int4(q[0], q[1], q[2], q[3]);
  }
}

// ---- main: one wave per node; gates redistributed via LDS so V is read
// as 6 x dwordx4 per lane (1 KB payload/instr) instead of 24 scalars.
// launch_bounds(256,3): 168-VGPR cap -- v7's (256,4)=128 forced spills
// (hand-counted peak liveness ~135-140). ----
__global__ __launch_bounds__(256, 3) void deepdft_v8(
    const float* __restrict__ S, const float* __restrict__ V,
    const float* __restrict__ EXPN, const float* __restrict__ DIR,
    const float* __restrict__ MASK, const float* __restrict__ DIST,
    const float* __restrict__ B1, const float* __restrict__ B2,
    const int4* __restrict__ wsf,
    float* __restrict__ OUT, int n_nodes)
{
  __shared__ int4  wlds[14][64];
  __shared__ float glds[4][16 * GSTR];   // per-wave gate buffer (ga,gc pairs)

  const int tid = threadIdx.x, wid = tid >> 6, l = tid & 63;
  const int col16 = l & 15, c = l >> 4, kc = c << 3;
  const int er8 = l >> 2, fo = l & 3;    // V-phase lane mapping

  int n = blockIdx.x * 4 + wid;
  if (n >= n_nodes) n = n_nodes - 1;
  const int eb0 = n << 5, eb1 = eb0 + 16;

  // ---- pipeline registers ----
  float4 sS0, sS1, sE0, sE1;
  float4 vva[6];
  float dv, mv, drv;

  auto issueS = [&](int eb) {
    const float* sp = S + (size_t)(eb + col16) * 32 + kc;
    sS0 = *reinterpret_cast<const float4*>(sp);
    sS1 = *reinterpret_cast<const float4*>(sp + 4);
    const float* ep = EXPN + (size_t)(eb + col16) * 20;
    if (c < 2) {
      sE0 = *reinterpret_cast<const float4*>(ep + kc);
      sE1 = *reinterpret_cast<const float4*>(ep + kc + 4);
    } else if (c == 2) {
      sE0 = *reinterpret_cast<const float4*>(ep + 16);
      sE1 = make_float4(1.f, 0.f, 0.f, 0.f);   // k=20 slot = 1 -> +br
    } else {
      sE0 = make_float4(0.f, 0.f, 0.f, 0.f);
      sE1 = make_float4(0.f, 0.f, 0.f, 0.f);
    }
  };
  auto issueV = [&](int eb) {
    const float* vb = V + (size_t)(eb + er8) * 96 + fo * 8;
    vva[0] = *reinterpret_cast<const float4*>(vb);
    vva[1] = *reinterpret_cast<const float4*>(vb + 4);
    vva[2] = *reinterpret_cast<const float4*>(vb + 32);
    vva[3] = *reinterpret_cast<const float4*>(vb + 36);
    vva[4] = *reinterpret_cast<const float4*>(vb + 64);
    vva[5] = *reinterpret_cast<const float4*>(vb + 68);
  };
  auto issueDMR = [&](int eb) {
    dv  = DIST[eb + col16];                       // wv for er = col16
    mv  = MASK[eb + col16];
    drv = DIR[(size_t)eb * 3 + (l < 48 ? l : 47)];
  };

  // cold-start loads before staging: latency hidden by staging work
  issueS(eb0); issueDMR(eb0); issueV(eb0);

  // ---- stage weights (4 int4 loads/wave from pre-packed d_ws) ----
  #pragma unroll
  for (int t = wid; t < 14; t += 4) wlds[t][l] = wsf[t*64 + l];

  f32x4 b1a, b1b;
  {
    float4 t0 = *reinterpret_cast<const float4*>(B1 + 4*c);
    float4 t1 = *reinterpret_cast<const float4*>(B1 + 16 + 4*c);
    b1a[0]=t0.x; b1a[1]=t0.y; b1a[2]=t0.z; b1a[3]=t0.w;
    b1b[0]=t1.x; b1b[1]=t1.y; b1b[2]=t1.z; b1b[3]=t1.w;
  }
  float b2v[6];
  #pragma unroll
  for (int t = 0; t < 6; ++t) b2v[t] = B2[(t << 4) + col16];

  __syncthreads();

  float part[24];
  #pragma unroll
  for (int q = 0; q < 24; ++q) part[q] = 0.f;
  float accs0 = 0.f, accs1 = 0.f;
  float* gw = &glds[wid][0];
  const f32x4 z = {0.f, 0.f, 0.f, 0.f};

  #pragma unroll
  for (int it = 0; it < 2; ++it) {
    // ================= gate phase (D-layout lanes) =================
    bf16x8 bs = cvt8(sS0, sS1);
    bf16x8 ae = cvt8(sE0, sE1);
    if (it == 0) issueS(eb1);

    // hT: lane-local h row per edge
    f32x4 h0 = __builtin_amdgcn_mfma_f32_16x16x32_bf16(ldsfrag(&wlds[0][l]), bs, b1a, 0,0,0);
    f32x4 h1 = __builtin_amdgcn_mfma_f32_16x16x32_bf16(ldsfrag(&wlds[1][l]), bs, b1b, 0,0,0);
    bf16x8 ah;
    {
      union { bf16x8 v; __hip_bfloat162 h[4]; } u;
      u.h[0] = __float22bfloat162_rn(make_float2(silu_(h0[0]), silu_(h0[1])));
      u.h[1] = __float22bfloat162_rn(make_float2(silu_(h0[2]), silu_(h0[3])));
      u.h[2] = __float22bfloat162_rn(make_float2(silu_(h1[0]), silu_(h1[1])));
      u.h[3] = __float22bfloat162_rn(make_float2(silu_(h1[2]), silu_(h1[3])));
      ah = u.v;
    }

    // wv for this lane's er' = col16, then gather for er = 4c+r
    float wvl = 0.f;
    if (dv < 5.f) wvl = mv * 0.5f * (__cosf(0.62831853071795865f * dv) + 1.f);
    float wv0 = __shfl(wvl, 4*c + 0);
    float wv1 = __shfl(wvl, 4*c + 1);
    float wv2 = __shfl(wvl, 4*c + 2);
    float wv3 = __shfl(wvl, 4*c + 3);

    #pragma unroll
    for (int tt = 0; tt < 2; ++tt) {
      f32x4 rA = __builtin_amdgcn_mfma_f32_16x16x32_bf16(ae, ldsfrag(&wlds[ 8+tt][l]), z, 0,0,0);
      f32x4 rB = __builtin_amdgcn_mfma_f32_16x16x32_bf16(ae, ldsfrag(&wlds[10+tt][l]), z, 0,0,0);
      f32x4 rC = __builtin_amdgcn_mfma_f32_16x16x32_bf16(ae, ldsfrag(&wlds[12+tt][l]), z, 0,0,0);
      f32x4 lA = __builtin_amdgcn_mfma_f32_16x16x32_bf16(ah, ldsfrag(&wlds[ 2+tt][l]), z, 0,0,0);
      f32x4 lB = __builtin_amdgcn_mfma_f32_16x16x32_bf16(ah, ldsfrag(&wlds[ 4+tt][l]), z, 0,0,0);
      f32x4 lC = __builtin_amdgcn_mfma_f32_16x16x32_bf16(ah, ldsfrag(&wlds[ 6+tt][l]), z, 0,0,0);
      #pragma unroll
      for (int r = 0; r < 4; ++r) {
        const float wv = (r==0) ? wv0 : (r==1) ? wv1 : (r==2) ? wv2 : wv3;
        const float ga = wv * (lA[r] + b2v[tt])   * rA[r];
        const float gb = wv * (lB[r] + b2v[2+tt]) * rB[r];
        const float gc = wv * (lC[r] + b2v[4+tt]) * rC[r];
        if (tt == 0) accs0 += gb; else accs1 += gb;
        *reinterpret_cast<float2*>(
            &gw[(4*c + r) * GSTR + 2*(col16 + 16*tt)]) = make_float2(ga, gc);
      }
    }
    __builtin_amdgcn_wave_barrier();

    // ================= V phase (er8/fo lanes) =================
    float d0 = __shfl(drv, 3*er8 + 0);
    float d1 = __shfl(drv, 3*er8 + 1);
    float d2 = __shfl(drv, 3*er8 + 2);
    if (it == 0) issueDMR(eb1);

    float4 gp[4];
    #pragma unroll
    for (int k = 0; k < 4; ++k)
      gp[k] = *reinterpret_cast<const float4*>(&gw[er8 * GSTR + 16*fo + 4*k]);

    #pragma unroll
    for (int ax = 0; ax < 3; ++ax) {
      const float dax = (ax==0) ? d0 : (ax==1) ? d1 : d2;
      #pragma unroll
      for (int j = 0; j < 8; ++j) {
        const float vj  = vva[2*ax + (j>>2)][j&3];
        const float gaj = gp[j>>1][(j&1)*2];
        const float gcj = gp[j>>1][(j&1)*2 + 1];
        part[ax*8+j] = fmaf(vj, gaj, fmaf(dax, gcj, part[ax*8+j]));
      }
    }
    if (it == 0) issueV(eb1);
    __builtin_amdgcn_wave_barrier();   // next item's gate writes stay below
  }

  // ---- reduce over er (lanes stride 4) and store ----
  #pragma unroll
  for (int q = 0; q < 24; ++q) {
    part[q] += __shfl_xor(part[q], 4);
    part[q] += __shfl_xor(part[q], 8);
    part[q] += __shfl_xor(part[q], 16);
    part[q] += __shfl_xor(part[q], 32);
  }
  accs0 += __shfl_xor(accs0, 16); accs0 += __shfl_xor(accs0, 32);
  accs1 += __shfl_xor(accs1, 16); accs1 += __shfl_xor(accs1, 32);

  if (l < 16) {
    OUT[(size_t)n * 32 + col16]      = accs0;
    OUT[(size_t)n * 32 + 16 + col16] = accs1;
  }
  if (l < 4) {
    float* ov = OUT + (size_t)n_nodes * 32 + (size_t)n * 96 + 8*fo;
    #pragma unroll
    for (int ax = 0; ax < 3; ++ax) {
      *reinterpret_cast<float4*>(ov + ax*32) =
          make_float4(part[ax*8+0], part[ax*8+1], part[ax*8+2], part[ax*8+3]);
      *reinterpret_cast<float4*>(ov + ax*32 + 4) =
          make_float4(part[ax*8+4], part[ax*8+5], part[ax*8+6], part[ax*8+7]);
    }
  }
}

extern "C" void kernel_launch(void* const* d_in, const int* in_sizes, int n_in,
                              void* d_out, int out_size, void* d_ws, size_t ws_size,
                              hipStream_t stream) {
  const float* S    = (const float*)d_in[0];
  const float* V    = (const float*)d_in[1];
  const float* EXPN = (const float*)d_in[2];
  const float* DIR  = (const float*)d_in[3];
  const float* MASK = (const float*)d_in[4];
  const float* DIST = (const float*)d_in[5];
  const float* W1   = (const float*)d_in[6];
  const float* B1   = (const float*)d_in[7];
  const float* W2   = (const float*)d_in[8];
  const float* B2   = (const float*)d_in[9];
  const float* WR   = (const float*)d_in[10];
  const float* BR   = (const float*)d_in[11];
  float* OUT = (float*)d_out;
  int4* wsf = (int4*)d_ws;   // 14 KB packed weight fragments

  const int n_nodes = in_sizes[0] / 1024;            // 30000
  const int grid = (n_nodes + 3) / 4;                // 7500

  hipLaunchKernelGGL(pack_weights_kernel, dim3(1), dim3(256), 0, stream,
                     W1, W2, WR, BR, wsf);
  hipLaunchKernelGGL(deepdft_v8, dim3(grid), dim3(256), 0, stream,
                     S, V, EXPN, DIR, MASK, DIST, B1, B2, wsf, OUT, n_nodes);
}

// Round 9
// 109.384 us; speedup vs baseline: 1.4921x; 1.2188x over previous
//
#include <hip/hip_runtime.h>
#include <hip/hip_bf16.h>

typedef __attribute__((ext_vector_type(8))) short bf16x8;
typedef __attribute__((ext_vector_type(4))) float f32x4;

#define GSTR 68   // floats per er-row of gate buffer (32 f x 2 + 4 pad)

__device__ __forceinline__ short f2bf(float f) {
  unsigned u = __float_as_uint(f);
  u += 0x7fffu + ((u >> 16) & 1u);   // RNE to bf16
  return (short)(u >> 16);
}

__device__ __forceinline__ bf16x8 cvt8(float4 A, float4 B) {
  union { bf16x8 v; __hip_bfloat162 h[4]; } u;
  u.h[0] = __float22bfloat162_rn(make_float2(A.x, A.y));
  u.h[1] = __float22bfloat162_rn(make_float2(A.z, A.w));
  u.h[2] = __float22bfloat162_rn(make_float2(B.x, B.y));
  u.h[3] = __float22bfloat162_rn(make_float2(B.z, B.w));
  return u.v;
}

__device__ __forceinline__ bf16x8 ldsfrag(const int4* p) {
  union { int4 i; bf16x8 b; } u;
  u.i = *p;
  return u.b;
}

__device__ __forceinline__ float silu_(float x) {
  return __fdividef(x, 1.f + __expf(-x));
}

// ---- setup: pack the 14 MFMA weight-fragment tiles into d_ws (14 KB) ----
__global__ void pack_weights_kernel(
    const float* __restrict__ W1, const float* __restrict__ W2,
    const float* __restrict__ WR, const float* __restrict__ BR,
    int4* __restrict__ wsf)
{
  const int tid = threadIdx.x, wid = tid >> 6, l = tid & 63;
  const int col16 = l & 15, c = l >> 4, kc = c << 3;
  for (int t = wid; t < 14; t += 4) {
    int q[4];
    #pragma unroll
    for (int jj = 0; jj < 4; ++jj) {
      float f0, f1;
      if (t < 2) {                       // W1^T A-frags
        int k0 = kc + 2*jj;
        int co = (t << 4) + col16;
        f0 = W1[k0*32 + co]; f1 = W1[(k0+1)*32 + co];
      } else if (t < 8) {                // W2 B-frags, k permuted by pi(c,j)
        int j0 = 2*jj;
        int feat = (j0 < 4) ? (4*c + j0) : (16 + 4*c + (j0 - 4));
        int co = ((t-2) << 4) + col16;
        f0 = W2[feat*96 + co]; f1 = W2[(feat+1)*96 + co];
      } else {                           // WR B-frags, row20 = BR
        int k0 = kc + 2*jj;
        int co = ((t-8) << 4) + col16;
        f0 = (k0   < 20) ? WR[k0*96 + co]     : ((k0   == 20) ? BR[co] : 0.f);
        f1 = (k0+1 < 20) ? WR[(k0+1)*96 + co] : ((k0+1 == 20) ? BR[co] : 0.f);
      }
      q[jj] = ((int)(unsigned short)f2bf(f0)) |
              (((int)(unsigned short)f2bf(f1)) << 16);
    }
    wsf[t*64 + l] = make_int4(q[0], q[1], q[2], q[3]);
  }
}

// ---- main: one wave per node. Gate-predicated loads: edges with
// mask==0 or dist>=cutoff (~33%) never load S/EXPN/V -- their whole
// cache lines are dropped via exec-mask. Dead lanes carry zeros, and
// w==0 multiplies every contribution out exactly (bit-identical to ref).
__global__ __launch_bounds__(256, 3) void deepdft_v9(
    const float* __restrict__ S, const float* __restrict__ V,
    const float* __restrict__ EXPN, const float* __restrict__ DIR,
    const float* __restrict__ MASK, const float* __restrict__ DIST,
    const float* __restrict__ B1, const float* __restrict__ B2,
    const int4* __restrict__ wsf,
    float* __restrict__ OUT, int n_nodes)
{
  __shared__ int4  wlds[14][64];
  __shared__ float glds[4][16 * GSTR];   // per-wave gate buffer (ga,gc pairs)

  const int tid = threadIdx.x, wid = tid >> 6, l = tid & 63;
  const int col16 = l & 15, c = l >> 4, kc = c << 3;
  const int er8 = l >> 2, fo = l & 3;    // V-phase lane mapping

  int n = blockIdx.x * 4 + wid;
  if (n >= n_nodes) n = n_nodes - 1;
  const int eb0 = n << 5, eb1 = eb0 + 16;

  // ---- tiny gate inputs for BOTH halves, issued first ----
  float dv0 = DIST[eb0 + col16];
  float mv0 = MASK[eb0 + col16];
  float dv1 = DIST[eb1 + col16];
  float mv1 = MASK[eb1 + col16];
  float drv = DIR[(size_t)eb0 * 3 + (l < 48 ? l : 47)];

  // ---- stage weights (4 int4 loads/wave from pre-packed d_ws) ----
  #pragma unroll
  for (int t = wid; t < 14; t += 4) wlds[t][l] = wsf[t*64 + l];

  f32x4 b1a, b1b;
  {
    float4 t0 = *reinterpret_cast<const float4*>(B1 + 4*c);
    float4 t1 = *reinterpret_cast<const float4*>(B1 + 16 + 4*c);
    b1a[0]=t0.x; b1a[1]=t0.y; b1a[2]=t0.z; b1a[3]=t0.w;
    b1b[0]=t1.x; b1b[1]=t1.y; b1b[2]=t1.z; b1b[3]=t1.w;
  }
  float b2v[6];
  #pragma unroll
  for (int t = 0; t < 6; ++t) b2v[t] = B2[(t << 4) + col16];

  // ---- per-edge gates (edge = col16 of each half) ----
  float wvl0 = 0.f, wvl1 = 0.f;
  if (dv0 < 5.f) wvl0 = mv0 * 0.5f * (__cosf(0.62831853071795865f * dv0) + 1.f);
  if (dv1 < 5.f) wvl1 = mv1 * 0.5f * (__cosf(0.62831853071795865f * dv1) + 1.f);

  // ---- staged regs, zero-init so dead lanes hold exact zeros ----
  const float4 z4 = make_float4(0.f, 0.f, 0.f, 0.f);
  float4 sS0 = z4, sS1 = z4, sE0 = z4;
  float4 sE1 = (c == 2) ? make_float4(1.f, 0.f, 0.f, 0.f) : z4; // k=20 -> +br
  float4 vva[6];
  #pragma unroll
  for (int j = 0; j < 6; ++j) vva[j] = z4;

  auto issueS = [&](int eb) {
    const float* sp = S + (size_t)(eb + col16) * 32 + kc;
    sS0 = *reinterpret_cast<const float4*>(sp);
    sS1 = *reinterpret_cast<const float4*>(sp + 4);
    const float* ep = EXPN + (size_t)(eb + col16) * 20;
    if (c < 2) {
      sE0 = *reinterpret_cast<const float4*>(ep + kc);
      sE1 = *reinterpret_cast<const float4*>(ep + kc + 4);
    } else if (c == 2) {
      sE0 = *reinterpret_cast<const float4*>(ep + 16);   // sE1 keeps {1,0,0,0}
    }
  };
  auto issueV = [&](int eb) {
    const float* vb = V + (size_t)(eb + er8) * 96 + fo * 8;
    vva[0] = *reinterpret_cast<const float4*>(vb);
    vva[1] = *reinterpret_cast<const float4*>(vb + 4);
    vva[2] = *reinterpret_cast<const float4*>(vb + 32);
    vva[3] = *reinterpret_cast<const float4*>(vb + 36);
    vva[4] = *reinterpret_cast<const float4*>(vb + 64);
    vva[5] = *reinterpret_cast<const float4*>(vb + 68);
  };

  // predicated cold-start loads for half 0
  if (wvl0 != 0.f) issueS(eb0);
  {
    float wv_er = __shfl(wvl0, er8);
    if (wv_er != 0.f) issueV(eb0);
  }

  __syncthreads();

  float part[24];
  #pragma unroll
  for (int q = 0; q < 24; ++q) part[q] = 0.f;
  float accs0 = 0.f, accs1 = 0.f;
  float* gw = &glds[wid][0];
  const f32x4 z = {0.f, 0.f, 0.f, 0.f};

  #pragma unroll
  for (int it = 0; it < 2; ++it) {
    const float wvl = it ? wvl1 : wvl0;
    // ================= gate phase (D-layout lanes) =================
    bf16x8 bs = cvt8(sS0, sS1);
    bf16x8 ae = cvt8(sE0, sE1);
    if (it == 0 && wvl1 != 0.f) issueS(eb1);   // predicated prefetch

    // hT: lane-local h row per edge
    f32x4 h0 = __builtin_amdgcn_mfma_f32_16x16x32_bf16(ldsfrag(&wlds[0][l]), bs, b1a, 0,0,0);
    f32x4 h1 = __builtin_amdgcn_mfma_f32_16x16x32_bf16(ldsfrag(&wlds[1][l]), bs, b1b, 0,0,0);
    bf16x8 ah;
    {
      union { bf16x8 v; __hip_bfloat162 h[4]; } u;
      u.h[0] = __float22bfloat162_rn(make_float2(silu_(h0[0]), silu_(h0[1])));
      u.h[1] = __float22bfloat162_rn(make_float2(silu_(h0[2]), silu_(h0[3])));
      u.h[2] = __float22bfloat162_rn(make_float2(silu_(h1[0]), silu_(h1[1])));
      u.h[3] = __float22bfloat162_rn(make_float2(silu_(h1[2]), silu_(h1[3])));
      ah = u.v;
    }

    // per-edge gate for er = 4c+r
    float wv0 = __shfl(wvl, 4*c + 0);
    float wv1 = __shfl(wvl, 4*c + 1);
    float wv2 = __shfl(wvl, 4*c + 2);
    float wv3 = __shfl(wvl, 4*c + 3);

    #pragma unroll
    for (int tt = 0; tt < 2; ++tt) {
      f32x4 rA = __builtin_amdgcn_mfma_f32_16x16x32_bf16(ae, ldsfrag(&wlds[ 8+tt][l]), z, 0,0,0);
      f32x4 rB = __builtin_amdgcn_mfma_f32_16x16x32_bf16(ae, ldsfrag(&wlds[10+tt][l]), z, 0,0,0);
      f32x4 rC = __builtin_amdgcn_mfma_f32_16x16x32_bf16(ae, ldsfrag(&wlds[12+tt][l]), z, 0,0,0);
      f32x4 lA = __builtin_amdgcn_mfma_f32_16x16x32_bf16(ah, ldsfrag(&wlds[ 2+tt][l]), z, 0,0,0);
      f32x4 lB = __builtin_amdgcn_mfma_f32_16x16x32_bf16(ah, ldsfrag(&wlds[ 4+tt][l]), z, 0,0,0);
      f32x4 lC = __builtin_amdgcn_mfma_f32_16x16x32_bf16(ah, ldsfrag(&wlds[ 6+tt][l]), z, 0,0,0);
      #pragma unroll
      for (int r = 0; r < 4; ++r) {
        const float wv = (r==0) ? wv0 : (r==1) ? wv1 : (r==2) ? wv2 : wv3;
        const float ga = wv * (lA[r] + b2v[tt])   * rA[r];
        const float gb = wv * (lB[r] + b2v[2+tt]) * rB[r];
        const float gc = wv * (lC[r] + b2v[4+tt]) * rC[r];
        if (tt == 0) accs0 += gb; else accs1 += gb;
        *reinterpret_cast<float2*>(
            &gw[(4*c + r) * GSTR + 2*(col16 + 16*tt)]) = make_float2(ga, gc);
      }
    }
    __builtin_amdgcn_wave_barrier();

    // ================= V phase (er8/fo lanes) =================
    float d0 = __shfl(drv, 3*er8 + 0);
    float d1 = __shfl(drv, 3*er8 + 1);
    float d2 = __shfl(drv, 3*er8 + 2);
    if (it == 0) drv = DIR[(size_t)eb1 * 3 + (l < 48 ? l : 47)];

    float4 gp[4];
    #pragma unroll
    for (int k = 0; k < 4; ++k)
      gp[k] = *reinterpret_cast<const float4*>(&gw[er8 * GSTR + 16*fo + 4*k]);

    #pragma unroll
    for (int ax = 0; ax < 3; ++ax) {
      const float dax = (ax==0) ? d0 : (ax==1) ? d1 : d2;
      #pragma unroll
      for (int j = 0; j < 8; ++j) {
        const float vj  = vva[2*ax + (j>>2)][j&3];
        const float gaj = gp[j>>1][(j&1)*2];
        const float gcj = gp[j>>1][(j&1)*2 + 1];
        part[ax*8+j] = fmaf(vj, gaj, fmaf(dax, gcj, part[ax*8+j]));
      }
    }
    if (it == 0) {
      float wv_er = __shfl(wvl1, er8);
      if (wv_er != 0.f) issueV(eb1);   // predicated prefetch
    }
    __builtin_amdgcn_wave_barrier();   // next item's gate writes stay below
  }

  // ---- reduce over er (lanes stride 4) and store ----
  #pragma unroll
  for (int q = 0; q < 24; ++q) {
    part[q] += __shfl_xor(part[q], 4);
    part[q] += __shfl_xor(part[q], 8);
    part[q] += __shfl_xor(part[q], 16);
    part[q] += __shfl_xor(part[q], 32);
  }
  accs0 += __shfl_xor(accs0, 16); accs0 += __shfl_xor(accs0, 32);
  accs1 += __shfl_xor(accs1, 16); accs1 += __shfl_xor(accs1, 32);

  if (l < 16) {
    OUT[(size_t)n * 32 + col16]      = accs0;
    OUT[(size_t)n * 32 + 16 + col16] = accs1;
  }
  if (l < 4) {
    float* ov = OUT + (size_t)n_nodes * 32 + (size_t)n * 96 + 8*fo;
    #pragma unroll
    for (int ax = 0; ax < 3; ++ax) {
      *reinterpret_cast<float4*>(ov + ax*32) =
          make_float4(part[ax*8+0], part[ax*8+1], part[ax*8+2], part[ax*8+3]);
      *reinterpret_cast<float4*>(ov + ax*32 + 4) =
          make_float4(part[ax*8+4], part[ax*8+5], part[ax*8+6], part[ax*8+7]);
    }
  }
}

extern "C" void kernel_launch(void* const* d_in, const int* in_sizes, int n_in,
                              void* d_out, int out_size, void* d_ws, size_t ws_size,
                              hipStream_t stream) {
  const float* S    = (const float*)d_in[0];
  const float* V    = (const float*)d_in[1];
  const float* EXPN = (const float*)d_in[2];
  const float* DIR  = (const float*)d_in[3];
  const float* MASK = (const float*)d_in[4];
  const float* DIST = (const float*)d_in[5];
  const float* W1   = (const float*)d_in[6];
  const float* B1   = (const float*)d_in[7];
  const float* W2   = (const float*)d_in[8];
  const float* B2   = (const float*)d_in[9];
  const float* WR   = (const float*)d_in[10];
  const float* BR   = (const float*)d_in[11];
  float* OUT = (float*)d_out;
  int4* wsf = (int4*)d_ws;   // 14 KB packed weight fragments

  const int n_nodes = in_sizes[0] / 1024;            // 30000
  const int grid = (n_nodes + 3) / 4;                // 7500

  hipLaunchKernelGGL(pack_weights_kernel, dim3(1), dim3(256), 0, stream,
                     W1, W2, WR, BR, wsf);
  hipLaunchKernelGGL(deepdft_v9, dim3(grid), dim3(256), 0, stream,
                     S, V, EXPN, DIR, MASK, DIST, B1, B2, wsf, OUT, n_nodes);
}